// Round 7
// baseline (79.814 us; speedup 1.0000x reference)
//
#include <hip/hip_runtime.h>
#include <math.h>

// TrackCrossAttention, 3-kernel fused form:
//   wqkT[n=h*64+d][i] = ns[i] * sum_e wq[i][h*64+e]*wk[d][h*64+e]  (bf16, transposed, nscale folded)
//   bqk[n]            = sum_e bq[h*64+e]*wk[d][h*64+e]
//   wvoT[j][h*64+d]   = sum_e wv[d][h*64+e]*wo[h*64+e][j]          (bf16, transposed)
//   bvo[j]            = sum_e bv[e]*wo[e][j] + bo[j]
// kprep(192): weight folding.
// kF(512): per (m=128 tok, head nt): stage bf16(x) + ssq -> GEMM1 -> qw=r*acc+bqk
//          -> in-kernel per-head attention (tf dbuf phases) -> wtf bf16 to ws.
// kG2(512): out = x + wtf @ wvoT + bvo  (f32, resid reg-prefetch).

#define NTOK 8192

typedef __attribute__((ext_vector_type(8))) short short8;
typedef __attribute__((ext_vector_type(8))) unsigned short ushort8;
typedef __attribute__((ext_vector_type(2))) unsigned short ushort2v;
typedef __attribute__((ext_vector_type(4))) float f32x4;

__device__ __forceinline__ unsigned short f2bf(float f) {
    unsigned int u = __float_as_uint(f);
    unsigned int r = (u + 0x7fffu + ((u >> 16) & 1u)) >> 16;
    return (unsigned short)r;
}
__device__ __forceinline__ float bf2f(unsigned short s) {
    return __uint_as_float(((unsigned int)s) << 16);
}
__device__ __forceinline__ void gl_lds16(const void* g, void* l) {
    __builtin_amdgcn_global_load_lds(
        (const __attribute__((address_space(1))) unsigned int*)g,
        (__attribute__((address_space(3))) unsigned int*)l,
        16, 0, 0);
}

// ---------------- weight folding ----------------

__global__ __launch_bounds__(256) void kprep(
    const float* __restrict__ wq, const float* __restrict__ bq,
    const float* __restrict__ wk, const float* __restrict__ wv,
    const float* __restrict__ bv, const float* __restrict__ wo,
    const float* __restrict__ bo, const float* __restrict__ nscale,
    unsigned short* __restrict__ wqkT, float* __restrict__ bqk,
    unsigned short* __restrict__ wvoT, float* __restrict__ bvo)
{
    const int bid = blockIdx.x;
    const int t = threadIdx.x;
    if (bid < 64) {
        __shared__ float wkL[64][65];
        __shared__ float wqL[64][65];
        const int h = bid >> 3;
        const int i0 = (bid & 7) * 64;
        #pragma unroll
        for (int i = 0; i < 16; ++i) {
            const int idx = t + i * 256;
            const int d = idx >> 6, e = idx & 63;
            wkL[d][e] = wk[(size_t)d * 512 + h * 64 + e];
            wqL[d][e] = wq[(size_t)(i0 + d) * 512 + h * 64 + e];
        }
        __syncthreads();
        const int d = t & 63, ig = t >> 6;
        float acc[16];
        #pragma unroll
        for (int ii = 0; ii < 16; ++ii) acc[ii] = 0.f;
        for (int e = 0; e < 64; ++e) {
            const float kv = wkL[d][e];
            #pragma unroll
            for (int ii = 0; ii < 16; ++ii)
                acc[ii] += kv * wqL[ig * 16 + ii][e];
        }
        #pragma unroll
        for (int ii = 0; ii < 16; ++ii) {
            const int i = i0 + ig * 16 + ii;
            wqkT[(size_t)(h * 64 + d) * 512 + i] = f2bf(acc[ii] * nscale[i]);
        }
        if (((bid & 7) == 0) && ig == 0) {
            float a = 0.f;
            #pragma unroll
            for (int e = 0; e < 64; ++e) a += bq[h * 64 + e] * wkL[d][e];
            bqk[h * 64 + d] = a;
        }
    } else if (bid < 128) {
        __shared__ float wvL[64][65];
        __shared__ float woL[64][65];
        const int b2 = bid - 64;
        const int h = b2 >> 3;
        const int j0 = (b2 & 7) * 64;
        #pragma unroll
        for (int i = 0; i < 16; ++i) {
            const int idx = t + i * 256;
            const int a = idx >> 6, b = idx & 63;
            wvL[a][b] = wv[(size_t)a * 512 + h * 64 + b];
            woL[a][b] = wo[(size_t)(h * 64 + a) * 512 + j0 + b];
        }
        __syncthreads();
        const int jloc = t & 63, dg = t >> 6;
        float acc[16];
        #pragma unroll
        for (int dd = 0; dd < 16; ++dd) acc[dd] = 0.f;
        for (int e = 0; e < 64; ++e) {
            const float b = woL[e][jloc];
            #pragma unroll
            for (int dd = 0; dd < 16; ++dd)
                acc[dd] += wvL[dg * 16 + dd][e] * b;
        }
        #pragma unroll
        for (int dd = 0; dd < 16; ++dd)
            wvoT[(size_t)(j0 + jloc) * 512 + h * 64 + dg * 16 + dd] = f2bf(acc[dd]);
    } else {
        const int b3 = bid - 128;
        const int j = b3 * 8 + (t >> 5);
        const int l = t & 31;
        float p = 0.f;
        #pragma unroll 4
        for (int e = l; e < 512; e += 32) p += bv[e] * wo[(size_t)e * 512 + j];
        #pragma unroll
        for (int m = 1; m < 32; m <<= 1) p += __shfl_xor(p, m, 64);
        if (l == 0) bvo[j] = bo[j] + p;
    }
}

// ---------------- fused: bf16(x) stage + GEMM1 + RMS-apply + attention ----------------

__global__ __launch_bounds__(256) void kF(
    const float* __restrict__ x, const float* __restrict__ track,
    const unsigned short* __restrict__ wqkT, const float* __restrict__ bqk,
    unsigned short* __restrict__ wtfb)
{
    // pool map: K-phase  Asm = [0,32K) (2x16K), Bsm = [32K,48K) (2x8K)
    //           attn     QW  = [0,16K), TF0 = [16K,48K), TF1 = [48K,80K)
    //           rls (128 f32) at pool+49152, inside TF1, dead before stage(1)
    __shared__ __align__(16) char pool[81920];
    const int tid = threadIdx.x;
    const int hw = blockIdx.x;
    const int logical = (hw & 7) * 64 + (hw >> 3);   // XCD swizzle, 512 % 8 == 0
    const int mt = logical >> 3, nt = logical & 7;
    const int tok0 = mt * 128, n0 = nt * 64;
    const int w = tid >> 6, lane = tid & 63;
    const int wr = w >> 1, wc = w & 1;
    const int lrow = lane & 15, lk = lane >> 4;
    float* rls = (float*)(pool + 49152);

    float pb[2];
    #pragma unroll
    for (int n = 0; n < 2; ++n) pb[n] = bqk[n0 + wc * 32 + n * 16 + lrow];

    // A reg-staging roles: row = tid>>1, 4 chunks (32 cols) per thread
    const int arow = tid >> 1;
    const int ac0 = (tid & 1) * 4;
    const float* xrow = x + (size_t)(tok0 + arow) * 512 + ac0 * 8;

    auto stageB = [&](int buf, int k0) {
        #pragma unroll
        for (int i = 0; i < 2; ++i) {
            const int f = tid + i * 256;
            const int row = f >> 3, c8 = f & 7;
            const int c8s = c8 ^ (row & 7);
            gl_lds16(wqkT + (size_t)(n0 + row) * 512 + k0 + c8s * 8,
                     pool + 32768 + buf * 8192 + f * 16);
        }
    };

    float ssq = 0.f;
    float4 v[8];
    auto packA = [&](int buf) {
        #pragma unroll
        for (int c2 = 0; c2 < 4; ++c2) {
            const float4 a0 = v[c2 * 2], a1 = v[c2 * 2 + 1];
            ssq += a0.x*a0.x + a0.y*a0.y + a0.z*a0.z + a0.w*a0.w
                 + a1.x*a1.x + a1.y*a1.y + a1.z*a1.z + a1.w*a1.w;
            ushort8 o;
            o[0]=f2bf(a0.x); o[1]=f2bf(a0.y); o[2]=f2bf(a0.z); o[3]=f2bf(a0.w);
            o[4]=f2bf(a1.x); o[5]=f2bf(a1.y); o[6]=f2bf(a1.z); o[7]=f2bf(a1.w);
            *reinterpret_cast<ushort8*>(
                pool + buf * 16384 + arow * 128 + (((ac0 + c2) ^ (arow & 7)) << 4)) = o;
        }
    };

    // prologue
    #pragma unroll
    for (int j = 0; j < 8; ++j) v[j] = *reinterpret_cast<const float4*>(xrow + j * 4);
    stageB(0, 0);
    packA(0);
    __syncthreads();

    f32x4 acc[4][2] = {};
    for (int it = 0; it < 8; ++it) {
        const int cur = it & 1;
        if (it < 7) {
            stageB(cur ^ 1, (it + 1) * 64);
            #pragma unroll
            for (int j = 0; j < 8; ++j)
                v[j] = *reinterpret_cast<const float4*>(xrow + (it + 1) * 64 + j * 4);
        }
        #pragma unroll
        for (int kk = 0; kk < 2; ++kk) {
            short8 a[4], b[2];
            #pragma unroll
            for (int m = 0; m < 4; ++m) {
                const int r = wr * 64 + m * 16 + lrow;
                const int byte = (r * 128 + kk * 64 + lk * 16) ^ ((r & 7) << 4);
                a[m] = *reinterpret_cast<const short8*>(pool + cur * 16384 + byte);
            }
            #pragma unroll
            for (int n = 0; n < 2; ++n) {
                const int rB = wc * 32 + n * 16 + lrow;
                const int byte = (rB * 128 + kk * 64 + lk * 16) ^ ((rB & 7) << 4);
                b[n] = *reinterpret_cast<const short8*>(pool + 32768 + cur * 8192 + byte);
            }
            #pragma unroll
            for (int m = 0; m < 4; ++m)
                #pragma unroll
                for (int n = 0; n < 2; ++n)
                    acc[m][n] = __builtin_amdgcn_mfma_f32_16x16x32_bf16(
                        a[m], b[n], acc[m][n], 0, 0, 0);
        }
        if (it < 7) packA(cur ^ 1);
        __syncthreads();
    }

    // row rms factors
    {
        const float tot = ssq + __shfl_xor(ssq, 1, 64);
        if ((tid & 1) == 0) rls[arow] = rsqrtf(tot * (1.f / 512.f) + 1e-6f);
    }
    __syncthreads();

    auto stageTF = [&](int pbuf, int p) {
        char* base = pool + 16384 + pbuf * 32768;
        #pragma unroll
        for (int i = 0; i < 8; ++i) {
            const int f = tid + i * 256;          // 0..2047
            const int tl = f >> 8, t = (f >> 4) & 15, dc = f & 15;
            const int token = tok0 + p * 8 + tl;
            const int bb = token >> 12, cc = token & 4095;
            const int dcs = dc ^ (t & 7);          // source-side swizzle (rule #21)
            gl_lds16(track + ((size_t)(bb * 16 + t) * 4096 + cc) * 64 + dcs * 4,
                     base + f * 16);
        }
    };
    stageTF(0, 0);   // overlaps epilogue below

    // epilogue: QW = bf16(r*acc + bqk) into pool[0,16K)
    #pragma unroll
    for (int n = 0; n < 2; ++n) {
        const int col = wc * 32 + n * 16 + lrow;
        #pragma unroll
        for (int m = 0; m < 4; ++m) {
            #pragma unroll
            for (int r2 = 0; r2 < 4; ++r2) {
                const int row = wr * 64 + m * 16 + lk * 4 + r2;
                const float qv = acc[m][n][r2] * rls[row] + pb[n];
                *reinterpret_cast<unsigned short*>(
                    pool + row * 128 + (((col >> 3) ^ (row & 7)) << 4) + (col & 7) * 2) = f2bf(qv);
            }
        }
    }
    __syncthreads();   // QW + TF0 ready (vmcnt drained)

    // attention: 16 phases x 8 tokens, one head (n0)
    const int tl = tid >> 5;
    const int sub = tid & 31;
    const int tslot = sub & 15, half = sub >> 4;
    const int dpv = sub * 2;
    for (int p = 0; p < 16; ++p) {
        if (p < 15) stageTF((p + 1) & 1, p + 1);
        const char* TFb = pool + 16384 + (p & 1) * 32768;
        const char* tokb = TFb + tl * 4096;
        const int qrow = p * 8 + tl;
        float qf[32];
        #pragma unroll
        for (int jq = 0; jq < 4; ++jq) {
            const ushort8 qv = *reinterpret_cast<const ushort8*>(
                pool + qrow * 128 + (((half * 4 + jq) ^ (qrow & 7)) << 4));
            #pragma unroll
            for (int e = 0; e < 8; ++e) qf[jq * 8 + e] = bf2f((unsigned short)qv[e]);
        }
        float acc1 = 0.f;
        #pragma unroll
        for (int jj = 0; jj < 8; ++jj) {
            const float4 tv = *reinterpret_cast<const float4*>(
                tokb + tslot * 256 + (((half * 8 + jj) ^ (tslot & 7)) << 4));
            acc1 += qf[jj*4+0]*tv.x + qf[jj*4+1]*tv.y + qf[jj*4+2]*tv.z + qf[jj*4+3]*tv.w;
        }
        acc1 += __shfl_xor(acc1, 16, 64);        // combine halves
        const float lg = acc1 * 0.125f;          // 1/sqrt(64)
        float mx = lg;
        #pragma unroll
        for (int msk = 1; msk < 16; msk <<= 1) mx = fmaxf(mx, __shfl_xor(mx, msk, 64));
        const float ev = __expf(lg - mx);
        float sm = ev;
        #pragma unroll
        for (int msk = 1; msk < 16; msk <<= 1) sm += __shfl_xor(sm, msk, 64);
        const float wgt = ev / sm;
        float o0 = 0.f, o1 = 0.f;
        #pragma unroll
        for (int t = 0; t < 16; ++t) {
            const float wt = __shfl(wgt, (lane & 48) + t, 64);
            const float2 tv = *reinterpret_cast<const float2*>(
                tokb + t * 256 + (((dpv >> 2) ^ (t & 7)) << 4) + (dpv & 3) * 4);
            o0 += wt * tv.x; o1 += wt * tv.y;
        }
        ushort2v ow; ow[0] = f2bf(o0); ow[1] = f2bf(o1);
        const int token = tok0 + p * 8 + tl;
        *reinterpret_cast<ushort2v*>(wtfb + (size_t)token * 512 + n0 + dpv) = ow;
        __syncthreads();
    }
}

// ---------------- GEMM2: out = x + wtf @ wvoT + bvo ----------------

__global__ __launch_bounds__(256) void kG2(
    const unsigned short* __restrict__ A,
    const unsigned short* __restrict__ Bt,
    const float* __restrict__ bias,
    const float* __restrict__ resid,
    float* __restrict__ out)
{
    __shared__ __align__(16) unsigned short Asm[2][128 * 64];
    __shared__ __align__(16) unsigned short Bsm[2][64 * 64];
    const int tid = threadIdx.x;
    const int hw = blockIdx.x;
    const int logical = (hw & 7) * 64 + (hw >> 3);
    const int mt = logical >> 3, nt = logical & 7;
    const int tok0 = mt * 128, n0 = nt * 64;
    const int w = tid >> 6, lane = tid & 63;
    const int wr = w >> 1, wc = w & 1;
    const int lrow = lane & 15, lk = lane >> 4;

    float pb[2];
    float rr[2][4][4];
    #pragma unroll
    for (int n = 0; n < 2; ++n) {
        const int ocol = n0 + wc * 32 + n * 16 + lrow;
        pb[n] = bias[ocol];
        #pragma unroll
        for (int m = 0; m < 4; ++m)
            #pragma unroll
            for (int r = 0; r < 4; ++r) {
                const int orow = tok0 + wr * 64 + m * 16 + lk * 4 + r;
                rr[n][m][r] = resid[(size_t)orow * 512 + ocol];
            }
    }

    const int srowA[4] = { (tid + 0) >> 3, (tid + 256) >> 3, (tid + 512) >> 3, (tid + 768) >> 3 };
    const int sc8 = tid & 7;
    auto STAGE = [&](int buf, int k0) {
        #pragma unroll
        for (int i = 0; i < 4; ++i) {
            const int f = tid + i * 256;
            const int row = srowA[i];
            const int c8s = sc8 ^ (row & 7);
            gl_lds16(A + (size_t)(tok0 + row) * 512 + k0 + c8s * 8,
                     (char*)&Asm[buf][0] + f * 16);
        }
        #pragma unroll
        for (int i = 0; i < 2; ++i) {
            const int f = tid + i * 256;
            const int row = f >> 3;
            const int c8s = sc8 ^ (row & 7);
            gl_lds16(Bt + (size_t)(n0 + row) * 512 + k0 + c8s * 8,
                     (char*)&Bsm[buf][0] + f * 16);
        }
    };

    f32x4 acc[4][2] = {};
    STAGE(0, 0);
    __syncthreads();
    for (int it = 0; it < 8; ++it) {
        const int cur = it & 1;
        if (it < 7) STAGE(cur ^ 1, (it + 1) * 64);
        #pragma unroll
        for (int kk = 0; kk < 2; ++kk) {
            short8 a[4], b[2];
            #pragma unroll
            for (int m = 0; m < 4; ++m) {
                const int r = wr * 64 + m * 16 + lrow;
                const int byte = (r * 128 + kk * 64 + lk * 16) ^ ((r & 7) << 4);
                a[m] = *reinterpret_cast<const short8*>((const char*)&Asm[cur][0] + byte);
            }
            #pragma unroll
            for (int n = 0; n < 2; ++n) {
                const int r = wc * 32 + n * 16 + lrow;
                const int byte = (r * 128 + kk * 64 + lk * 16) ^ ((r & 7) << 4);
                b[n] = *reinterpret_cast<const short8*>((const char*)&Bsm[cur][0] + byte);
            }
            #pragma unroll
            for (int m = 0; m < 4; ++m)
                #pragma unroll
                for (int n = 0; n < 2; ++n)
                    acc[m][n] = __builtin_amdgcn_mfma_f32_16x16x32_bf16(
                        a[m], b[n], acc[m][n], 0, 0, 0);
        }
        __syncthreads();
    }
    #pragma unroll
    for (int n = 0; n < 2; ++n) {
        const int ocol = n0 + wc * 32 + n * 16 + lrow;
        #pragma unroll
        for (int m = 0; m < 4; ++m) {
            #pragma unroll
            for (int r = 0; r < 4; ++r) {
                const int orow = tok0 + wr * 64 + m * 16 + lk * 4 + r;
                out[(size_t)orow * 512 + ocol] = acc[m][n][r] + pb[n] + rr[n][m][r];
            }
        }
    }
}

extern "C" void kernel_launch(void* const* d_in, const int* in_sizes, int n_in,
                              void* d_out, int out_size, void* d_ws, size_t ws_size,
                              hipStream_t stream) {
    const float* x      = (const float*)d_in[0];
    const float* track  = (const float*)d_in[1];
    const float* nscale = (const float*)d_in[2];
    const float* wq     = (const float*)d_in[3];
    const float* bq     = (const float*)d_in[4];
    const float* wk     = (const float*)d_in[5];
    // d_in[6] = bk: constant over t per head -> softmax-invariant, omitted exactly
    const float* wv     = (const float*)d_in[7];
    const float* bv     = (const float*)d_in[8];
    const float* wo     = (const float*)d_in[9];
    const float* bo     = (const float*)d_in[10];
    float* buf = (float*)d_out;

    char* ws = (char*)d_ws;
    unsigned short* wtfb = (unsigned short*)ws;                // 8 MB
    unsigned short* wqkT = (unsigned short*)(ws + 8388608);    // 512 KB
    unsigned short* wvoT = (unsigned short*)(ws + 8912896);    // 512 KB
    float* bqk = (float*)(ws + 9437184);                       // 2 KB
    float* bvo = (float*)(ws + 9439232);                       // 2 KB

    kprep<<<192, 256, 0, stream>>>(wq, bq, wk, wv, bv, wo, bo, nscale,
                                   wqkT, bqk, wvoT, bvo);
    kF<<<512, 256, 0, stream>>>(x, track, wqkT, bqk, wtfb);
    kG2<<<512, 256, 0, stream>>>(wtfb, wvoT, bvo, x, buf);
}

// Round 8
// 61.640 us; speedup vs baseline: 1.2948x; 1.2948x over previous
//
#include <hip/hip_runtime.h>
#include <math.h>

// TrackCrossAttention, 4-kernel form (round-6 structure, RMSNorm fused into GEMM1):
//   wqkT[n=h*64+d][i] = ns[i]*sum_e wq[i][h*64+e]*wk[d][h*64+e]  (bf16, T, nscale folded)
//   bqk[n]            = sum_e bq[h*64+e]*wk[d][h*64+e]
//   wvoT[j][h*64+d]   = sum_e wv[d][h*64+e]*wo[h*64+e][j]        (bf16, T)
//   bvo[j]            = sum_e bv[e]*wo[e][j] + bo[j]
// kprep(192): weight folding.
// kRG1(512): qw = RMSNorm(x) @ wqk + bqk, scaled by 1/8 -> bf16 ws  [reg-staged A, MFMA]
// k3(4096) : logits/softmax/wtf -> wtf bf16 ws
// kG2(512) : out = x + wtf @ wvo + bvo -> f32

#define NTOK 8192

typedef __attribute__((ext_vector_type(8))) short short8;
typedef __attribute__((ext_vector_type(8))) unsigned short ushort8;
typedef __attribute__((ext_vector_type(4))) unsigned short ushort4v;
typedef __attribute__((ext_vector_type(4))) float f32x4;

__device__ __forceinline__ unsigned short f2bf(float f) {
    unsigned int u = __float_as_uint(f);
    unsigned int r = (u + 0x7fffu + ((u >> 16) & 1u)) >> 16;
    return (unsigned short)r;
}
__device__ __forceinline__ float bf2f(unsigned short s) {
    return __uint_as_float(((unsigned int)s) << 16);
}
__device__ __forceinline__ void gl_lds16(const void* g, void* l) {
    __builtin_amdgcn_global_load_lds(
        (const __attribute__((address_space(1))) unsigned int*)g,
        (__attribute__((address_space(3))) unsigned int*)l,
        16, 0, 0);
}

// ---------------- weight folding ----------------

__global__ __launch_bounds__(256) void kprep(
    const float* __restrict__ wq, const float* __restrict__ bq,
    const float* __restrict__ wk, const float* __restrict__ wv,
    const float* __restrict__ bv, const float* __restrict__ wo,
    const float* __restrict__ bo, const float* __restrict__ nscale,
    unsigned short* __restrict__ wqkT, float* __restrict__ bqk,
    unsigned short* __restrict__ wvoT, float* __restrict__ bvo)
{
    const int bid = blockIdx.x;
    const int t = threadIdx.x;
    if (bid < 64) {
        __shared__ float wkL[64][65];
        __shared__ float wqL[64][65];
        const int h = bid >> 3;
        const int i0 = (bid & 7) * 64;
        #pragma unroll
        for (int i = 0; i < 16; ++i) {
            const int idx = t + i * 256;
            const int d = idx >> 6, e = idx & 63;
            wkL[d][e] = wk[(size_t)d * 512 + h * 64 + e];
            wqL[d][e] = wq[(size_t)(i0 + d) * 512 + h * 64 + e];
        }
        __syncthreads();
        const int d = t & 63, ig = t >> 6;
        float acc[16];
        #pragma unroll
        for (int ii = 0; ii < 16; ++ii) acc[ii] = 0.f;
        for (int e = 0; e < 64; ++e) {
            const float kv = wkL[d][e];
            #pragma unroll
            for (int ii = 0; ii < 16; ++ii)
                acc[ii] += kv * wqL[ig * 16 + ii][e];
        }
        #pragma unroll
        for (int ii = 0; ii < 16; ++ii) {
            const int i = i0 + ig * 16 + ii;
            wqkT[(size_t)(h * 64 + d) * 512 + i] = f2bf(acc[ii] * nscale[i]);
        }
        if (((bid & 7) == 0) && ig == 0) {
            float a = 0.f;
            #pragma unroll
            for (int e = 0; e < 64; ++e) a += bq[h * 64 + e] * wkL[d][e];
            bqk[h * 64 + d] = a;
        }
    } else if (bid < 128) {
        __shared__ float wvL[64][65];
        __shared__ float woL[64][65];
        const int b2 = bid - 64;
        const int h = b2 >> 3;
        const int j0 = (b2 & 7) * 64;
        #pragma unroll
        for (int i = 0; i < 16; ++i) {
            const int idx = t + i * 256;
            const int a = idx >> 6, b = idx & 63;
            wvL[a][b] = wv[(size_t)a * 512 + h * 64 + b];
            woL[a][b] = wo[(size_t)(h * 64 + a) * 512 + j0 + b];
        }
        __syncthreads();
        const int jloc = t & 63, dg = t >> 6;
        float acc[16];
        #pragma unroll
        for (int dd = 0; dd < 16; ++dd) acc[dd] = 0.f;
        for (int e = 0; e < 64; ++e) {
            const float b = woL[e][jloc];
            #pragma unroll
            for (int dd = 0; dd < 16; ++dd)
                acc[dd] += wvL[dg * 16 + dd][e] * b;
        }
        #pragma unroll
        for (int dd = 0; dd < 16; ++dd)
            wvoT[(size_t)(j0 + jloc) * 512 + h * 64 + dg * 16 + dd] = f2bf(acc[dd]);
    } else {
        const int b3 = bid - 128;
        const int j = b3 * 8 + (t >> 5);
        const int l = t & 31;
        float p = 0.f;
        #pragma unroll 4
        for (int e = l; e < 512; e += 32) p += bv[e] * wo[(size_t)e * 512 + j];
        #pragma unroll
        for (int m = 1; m < 32; m <<= 1) p += __shfl_xor(p, m, 64);
        if (l == 0) bvo[j] = bo[j] + p;
    }
}

// ---------------- kRG1: RMSNorm-fused GEMM1 ----------------
// qw = (diag(rsqrt(mean(x^2)+eps)) * bf16(x) @ wqkT + bqk) * 0.125 -> bf16

__global__ __launch_bounds__(256) void kRG1(
    const float* __restrict__ x,
    const unsigned short* __restrict__ wqkT, const float* __restrict__ bqk,
    unsigned short* __restrict__ qwb)
{
    __shared__ __align__(16) unsigned short Asm[2][128 * 64];
    __shared__ __align__(16) unsigned short Bsm[2][64 * 64];
    __shared__ float rls[128];
    const int tid = threadIdx.x;
    const int hw = blockIdx.x;
    const int logical = (hw & 7) * 64 + (hw >> 3);   // XCD swizzle (512 % 8 == 0)
    const int mt = logical >> 3, nt = logical & 7;
    const int tok0 = mt * 128, n0 = nt * 64;
    const int w = tid >> 6, lane = tid & 63;
    const int wr = w >> 1, wc = w & 1;
    const int lrow = lane & 15, lk = lane >> 4;

    float pb[2];
    #pragma unroll
    for (int n = 0; n < 2; ++n) pb[n] = bqk[n0 + wc * 32 + n * 16 + lrow];

    // A staging roles: j = tid>>4 (base row), c4 = tid&15 (float4 chunk)
    const int aj = tid >> 4, ac4 = tid & 15;
    const int sc8 = tid & 7;

    auto stageB = [&](int buf, int k0) {
        #pragma unroll
        for (int i = 0; i < 2; ++i) {
            const int f = tid + i * 256;
            const int row = f >> 3, c8 = f & 7;
            const int c8s = c8 ^ (row & 7);
            gl_lds16(wqkT + (size_t)(n0 + row) * 512 + k0 + c8s * 8,
                     (char*)&Bsm[buf][0] + f * 16);
        }
    };

    float ssq[8];
    #pragma unroll
    for (int i = 0; i < 8; ++i) ssq[i] = 0.f;
    float4 v[8];

    auto loadA = [&](int it) {
        #pragma unroll
        for (int i = 0; i < 8; ++i) {
            const int row = aj + 16 * i;
            v[i] = *reinterpret_cast<const float4*>(
                x + (size_t)(tok0 + row) * 512 + it * 64 + ac4 * 4);
        }
    };
    auto packA = [&](int buf) {
        #pragma unroll
        for (int i = 0; i < 8; ++i) {
            const int row = aj + 16 * i;
            ssq[i] += v[i].x*v[i].x + v[i].y*v[i].y + v[i].z*v[i].z + v[i].w*v[i].w;
            ushort4v o;
            o[0] = f2bf(v[i].x); o[1] = f2bf(v[i].y);
            o[2] = f2bf(v[i].z); o[3] = f2bf(v[i].w);
            *reinterpret_cast<ushort4v*>(
                (char*)&Asm[buf][0] + row * 128 + (((ac4 >> 1) ^ (row & 7)) << 4)
                + (ac4 & 1) * 8) = o;
        }
    };

    stageB(0, 0);
    loadA(0);
    packA(0);
    __syncthreads();

    f32x4 acc[4][2] = {};
    for (int it = 0; it < 8; ++it) {
        const int cur = it & 1;
        if (it < 7) {
            stageB(cur ^ 1, (it + 1) * 64);
            loadA(it + 1);
        }
        #pragma unroll
        for (int kk = 0; kk < 2; ++kk) {
            short8 a[4], b[2];
            #pragma unroll
            for (int m = 0; m < 4; ++m) {
                const int r = wr * 64 + m * 16 + lrow;
                const int byte = (r * 128 + kk * 64 + lk * 16) ^ ((r & 7) << 4);
                a[m] = *reinterpret_cast<const short8*>((const char*)&Asm[cur][0] + byte);
            }
            #pragma unroll
            for (int n = 0; n < 2; ++n) {
                const int rB = wc * 32 + n * 16 + lrow;
                const int byte = (rB * 128 + kk * 64 + lk * 16) ^ ((rB & 7) << 4);
                b[n] = *reinterpret_cast<const short8*>((const char*)&Bsm[cur][0] + byte);
            }
            #pragma unroll
            for (int m = 0; m < 4; ++m)
                #pragma unroll
                for (int n = 0; n < 2; ++n)
                    acc[m][n] = __builtin_amdgcn_mfma_f32_16x16x32_bf16(
                        a[m], b[n], acc[m][n], 0, 0, 0);
        }
        if (it < 7) packA(cur ^ 1);
        __syncthreads();
    }

    // per-row RMS factors: reduce ssq[i] across the 16-lane chunk group
    #pragma unroll
    for (int i = 0; i < 8; ++i) {
        #pragma unroll
        for (int msk = 1; msk < 16; msk <<= 1) ssq[i] += __shfl_xor(ssq[i], msk, 64);
    }
    if ((tid & 15) == 0) {
        #pragma unroll
        for (int i = 0; i < 8; ++i)
            rls[aj + 16 * i] = rsqrtf(ssq[i] * (1.f / 512.f) + 1e-6f);
    }
    __syncthreads();

    #pragma unroll
    for (int n = 0; n < 2; ++n) {
        const int ocol = n0 + wc * 32 + n * 16 + lrow;
        #pragma unroll
        for (int m = 0; m < 4; ++m) {
            #pragma unroll
            for (int r = 0; r < 4; ++r) {
                const int row = wr * 64 + m * 16 + lk * 4 + r;
                const float qv = (acc[m][n][r] * rls[row] + pb[n]) * 0.125f;
                qwb[(size_t)(tok0 + row) * 512 + ocol] = f2bf(qv);
            }
        }
    }
}

// ---------------- attention core: 2 tokens/block, parallel softmax ----------------

__global__ __launch_bounds__(256) void k3_attn(
    const float* __restrict__ track, const unsigned short* __restrict__ qwb,
    unsigned short* __restrict__ wtfb)
{
    __shared__ __align__(16) float tf[2][16][68];
    __shared__ __align__(16) float qwl[2][8][68];
    __shared__ float lw[2][8][16];
    const int tid = threadIdx.x;
    const int tok = tid >> 7;         // 0..1
    const int t2 = tid & 127;
    const int token = blockIdx.x * 2 + tok;
    const int b = token >> 12;        // C = 4096
    const int c = token & 4095;
    #pragma unroll
    for (int i = 0; i < 2; ++i) {
        const int f = t2 + i * 128;   // 0..255
        const int row = f >> 4, d4 = (f & 15) * 4;
        *reinterpret_cast<float4*>(&tf[tok][row][d4]) =
            *reinterpret_cast<const float4*>(track + ((size_t)(b * 16 + row) * 4096 + c) * 64 + d4);
    }
    if (t2 < 64) {
        const ushort8 q = *reinterpret_cast<const ushort8*>(qwb + (size_t)token * 512 + t2 * 8);
        #pragma unroll
        for (int j = 0; j < 8; ++j) {
            const int idx = t2 * 8 + j;
            qwl[tok][idx >> 6][idx & 63] = bf2f(q[j]);
        }
    }
    __syncthreads();
    {
        const int h = t2 >> 4, tt = t2 & 15;
        float acc = 0.f;
        #pragma unroll
        for (int d16 = 0; d16 < 16; ++d16) {
            const float4 qv = *reinterpret_cast<const float4*>(&qwl[tok][h][d16 * 4]);
            const float4 tv = *reinterpret_cast<const float4*>(&tf[tok][tt][d16 * 4]);
            acc += qv.x * tv.x + qv.y * tv.y + qv.z * tv.z + qv.w * tv.w;
        }
        const float lg = acc;          // 1/sqrt(64) folded into qw upstream
        float mx = lg;
        #pragma unroll
        for (int m = 1; m < 16; m <<= 1) mx = fmaxf(mx, __shfl_xor(mx, m, 64));
        const float ev = __expf(lg - mx);
        float sum = ev;
        #pragma unroll
        for (int m = 1; m < 16; m <<= 1) sum += __shfl_xor(sum, m, 64);
        lw[tok][h][tt] = ev / sum;
    }
    __syncthreads();
    {
        const int h = t2 >> 4;
        const int d0 = (t2 & 15) * 4;
        float o0 = 0.f, o1 = 0.f, o2 = 0.f, o3 = 0.f;
        #pragma unroll
        for (int t = 0; t < 16; ++t) {
            const float wgt = lw[tok][h][t];
            const float4 tv = *reinterpret_cast<const float4*>(&tf[tok][t][d0]);
            o0 += wgt * tv.x; o1 += wgt * tv.y; o2 += wgt * tv.z; o3 += wgt * tv.w;
        }
        ushort4v ov;
        ov[0] = f2bf(o0); ov[1] = f2bf(o1); ov[2] = f2bf(o2); ov[3] = f2bf(o3);
        *reinterpret_cast<ushort4v*>(wtfb + (size_t)token * 512 + t2 * 4) = ov;
    }
}

// ---------------- GEMM2: out = x + wtf @ wvoT + bvo ----------------

__global__ __launch_bounds__(256) void kG2(
    const unsigned short* __restrict__ A,
    const unsigned short* __restrict__ Bt,
    const float* __restrict__ bias,
    const float* __restrict__ resid,
    float* __restrict__ out)
{
    __shared__ __align__(16) unsigned short Asm[2][128 * 64];
    __shared__ __align__(16) unsigned short Bsm[2][64 * 64];
    const int tid = threadIdx.x;
    const int hw = blockIdx.x;
    const int logical = (hw & 7) * 64 + (hw >> 3);
    const int mt = logical >> 3, nt = logical & 7;
    const int tok0 = mt * 128, n0 = nt * 64;
    const int w = tid >> 6, lane = tid & 63;
    const int wr = w >> 1, wc = w & 1;
    const int lrow = lane & 15, lk = lane >> 4;

    float pb[2];
    float rr[2][4][4];
    #pragma unroll
    for (int n = 0; n < 2; ++n) {
        const int ocol = n0 + wc * 32 + n * 16 + lrow;
        pb[n] = bias[ocol];
        #pragma unroll
        for (int m = 0; m < 4; ++m)
            #pragma unroll
            for (int r = 0; r < 4; ++r) {
                const int orow = tok0 + wr * 64 + m * 16 + lk * 4 + r;
                rr[n][m][r] = resid[(size_t)orow * 512 + ocol];
            }
    }

    const int srowA[4] = { (tid + 0) >> 3, (tid + 256) >> 3, (tid + 512) >> 3, (tid + 768) >> 3 };
    const int sc8 = tid & 7;
    auto STAGE = [&](int buf, int k0) {
        #pragma unroll
        for (int i = 0; i < 4; ++i) {
            const int f = tid + i * 256;
            const int row = srowA[i];
            const int c8s = sc8 ^ (row & 7);
            gl_lds16(A + (size_t)(tok0 + row) * 512 + k0 + c8s * 8,
                     (char*)&Asm[buf][0] + f * 16);
        }
        #pragma unroll
        for (int i = 0; i < 2; ++i) {
            const int f = tid + i * 256;
            const int row = f >> 3;
            const int c8s = sc8 ^ (row & 7);
            gl_lds16(Bt + (size_t)(n0 + row) * 512 + k0 + c8s * 8,
                     (char*)&Bsm[buf][0] + f * 16);
        }
    };

    f32x4 acc[4][2] = {};
    STAGE(0, 0);
    __syncthreads();
    for (int it = 0; it < 8; ++it) {
        const int cur = it & 1;
        if (it < 7) STAGE(cur ^ 1, (it + 1) * 64);
        #pragma unroll
        for (int kk = 0; kk < 2; ++kk) {
            short8 a[4], b[2];
            #pragma unroll
            for (int m = 0; m < 4; ++m) {
                const int r = wr * 64 + m * 16 + lrow;
                const int byte = (r * 128 + kk * 64 + lk * 16) ^ ((r & 7) << 4);
                a[m] = *reinterpret_cast<const short8*>((const char*)&Asm[cur][0] + byte);
            }
            #pragma unroll
            for (int n = 0; n < 2; ++n) {
                const int r = wc * 32 + n * 16 + lrow;
                const int byte = (r * 128 + kk * 64 + lk * 16) ^ ((r & 7) << 4);
                b[n] = *reinterpret_cast<const short8*>((const char*)&Bsm[cur][0] + byte);
            }
            #pragma unroll
            for (int m = 0; m < 4; ++m)
                #pragma unroll
                for (int n = 0; n < 2; ++n)
                    acc[m][n] = __builtin_amdgcn_mfma_f32_16x16x32_bf16(
                        a[m], b[n], acc[m][n], 0, 0, 0);
        }
        __syncthreads();
    }
    #pragma unroll
    for (int n = 0; n < 2; ++n) {
        const int ocol = n0 + wc * 32 + n * 16 + lrow;
        #pragma unroll
        for (int m = 0; m < 4; ++m) {
            #pragma unroll
            for (int r = 0; r < 4; ++r) {
                const int orow = tok0 + wr * 64 + m * 16 + lk * 4 + r;
                out[(size_t)orow * 512 + ocol] = acc[m][n][r] + pb[n] + rr[n][m][r];
            }
        }
    }
}

extern "C" void kernel_launch(void* const* d_in, const int* in_sizes, int n_in,
                              void* d_out, int out_size, void* d_ws, size_t ws_size,
                              hipStream_t stream) {
    const float* x      = (const float*)d_in[0];
    const float* track  = (const float*)d_in[1];
    const float* nscale = (const float*)d_in[2];
    const float* wq     = (const float*)d_in[3];
    const float* bq     = (const float*)d_in[4];
    const float* wk     = (const float*)d_in[5];
    // d_in[6] = bk: constant over t per head -> softmax-invariant, omitted exactly
    const float* wv     = (const float*)d_in[7];
    const float* bv     = (const float*)d_in[8];
    const float* wo     = (const float*)d_in[9];
    const float* bo     = (const float*)d_in[10];
    float* buf = (float*)d_out;

    char* ws = (char*)d_ws;
    unsigned short* qwb  = (unsigned short*)ws;                // 8 MB
    unsigned short* wtfb = (unsigned short*)(ws + 8388608);    // 8 MB
    unsigned short* wqkT = (unsigned short*)(ws + 16777216);   // 512 KB
    unsigned short* wvoT = (unsigned short*)(ws + 17301504);   // 512 KB
    float* bqk = (float*)(ws + 17825792);                      // 2 KB
    float* bvo = (float*)(ws + 17827840);                      // 2 KB

    kprep<<<192, 256, 0, stream>>>(wq, bq, wk, wv, bv, wo, bo, nscale,
                                   wqkT, bqk, wvoT, bvo);
    kRG1<<<512, 256, 0, stream>>>(x, wqkT, bqk, qwb);
    k3_attn<<<NTOK / 2, 256, 0, stream>>>(track, qwb, wtfb);
    kG2<<<512, 256, 0, stream>>>(wtfb, wvoT, bvo, x, buf);
}